// Round 1
// baseline (320.497 us; speedup 1.0000x reference)
//
#include <hip/hip_runtime.h>
#include <cstdint>
#include <cstddef>

typedef __bf16 bf16_t;
typedef __bf16 bf16x8 __attribute__((ext_vector_type(8)));
typedef __bf16 bf16x4 __attribute__((ext_vector_type(4)));
typedef float f32x4 __attribute__((ext_vector_type(4)));

#define N_SEQ 2048
#define BATCH 2
#define EMB   1024
#define HID   1024
#define NHEAD 16
#define HDIM  64
#define NBROW (N_SEQ * BATCH)   /* 4096 GEMM rows (n*B+b) */
#define ATT_SCALE 0.03125f      /* 1/sqrt(1024) */

static __device__ __forceinline__ void async_copy16(const bf16_t* g, bf16_t* l) {
  __builtin_amdgcn_global_load_lds((const __attribute__((address_space(1))) void*)g,
                                   (__attribute__((address_space(3))) void*)l,
                                   16, 0, 0);
}

// ---------------- elementwise fp32 -> bf16 (4 elems/thread) ----------------
__global__ void convert_bf16_kernel(const float* __restrict__ in,
                                    bf16_t* __restrict__ out) {
  int i = (blockIdx.x * 256 + threadIdx.x) * 4;
  float4 v = *(const float4*)(in + i);
  bf16x4 o;
  o[0] = (bf16_t)v.x; o[1] = (bf16_t)v.y; o[2] = (bf16_t)v.z; o[3] = (bf16_t)v.w;
  *(bf16x4*)(out + i) = o;
}

// ------------- transpose + convert: in R x C fp32 -> out C x R bf16 --------
__global__ void transpose_convert_kernel(const float* __restrict__ in,
                                         bf16_t* __restrict__ out,
                                         int R, int C) {
  __shared__ float tile[32][33];
  int tx = threadIdx.x & 31, ty = threadIdx.x >> 5;   // 32 x 8 threads
  int bc = blockIdx.x * 32, br = blockIdx.y * 32;
  #pragma unroll
  for (int i = 0; i < 32; i += 8)
    tile[ty + i][tx] = in[(size_t)(br + ty + i) * C + bc + tx];
  __syncthreads();
  #pragma unroll
  for (int i = 0; i < 32; i += 8)
    out[(size_t)(bc + ty + i) * R + br + tx] = (bf16_t)tile[tx][ty + i];
}

// ---------------- GEMM: C[M][N] = A[M][K] * Bt[N][K]^T + bias --------------
// m97 recipe: 128x128 tile, BK=32, global_load_lds width 16, 2x2 waves,
// each wave 4x4 of 16x16x32 bf16 MFMA. A,Bt row-major bf16.
template <bool OUT_BF16>
__global__ __launch_bounds__(256) void gemm_bt_kernel(
    const bf16_t* __restrict__ A, const bf16_t* __restrict__ Bt,
    const float* __restrict__ bias, void* __restrict__ Cout,
    int M, int Nn, int K) {
  __shared__ __align__(16) bf16_t As[128 * 32];
  __shared__ __align__(16) bf16_t Bs[128 * 32];
  int tid = threadIdx.x;
  int wave = tid >> 6, lane = tid & 63;
  int c = lane & 15, quad = lane >> 4;
  int bm = blockIdx.x * 128;
  int bn = blockIdx.y * 128;
  int wm = (wave & 1) * 64, wn = (wave >> 1) * 64;
  f32x4 acc[4][4] = {};

  for (int kb = 0; kb < K; kb += 32) {
    #pragma unroll
    for (int i = 0; i < 2; ++i) {
      int e = (i * 256 + tid) * 8;           // elem index in 128x32 tile
      int row = e >> 5, kk = e & 31;
      async_copy16(A + (size_t)(bm + row) * K + kb + kk,
                   As + (size_t)(i * 256 + wave * 64) * 8);
      async_copy16(Bt + (size_t)(bn + row) * K + kb + kk,
                   Bs + (size_t)(i * 256 + wave * 64) * 8);
    }
    __syncthreads();
    bf16x8 af[4], bf[4];
    #pragma unroll
    for (int mt = 0; mt < 4; ++mt)
      af[mt] = *(const bf16x8*)(As + (wm + mt * 16 + c) * 32 + quad * 8);
    #pragma unroll
    for (int nt = 0; nt < 4; ++nt)
      bf[nt] = *(const bf16x8*)(Bs + (wn + nt * 16 + c) * 32 + quad * 8);
    #pragma unroll
    for (int mt = 0; mt < 4; ++mt)
      #pragma unroll
      for (int nt = 0; nt < 4; ++nt)
        acc[mt][nt] = __builtin_amdgcn_mfma_f32_16x16x32_bf16(
            af[mt], bf[nt], acc[mt][nt], 0, 0, 0);
    __syncthreads();
  }

  #pragma unroll
  for (int nt = 0; nt < 4; ++nt) {
    int col = bn + wn + nt * 16 + c;
    float bv = bias[col];
    #pragma unroll
    for (int mt = 0; mt < 4; ++mt) {
      #pragma unroll
      for (int r = 0; r < 4; ++r) {
        int row = bm + wm + mt * 16 + quad * 4 + r;   // C layout: row=(lane>>4)*4+reg
        float v = acc[mt][nt][r] + bv;
        if (OUT_BF16)
          ((bf16_t*)Cout)[(size_t)row * Nn + col] = (bf16_t)v;
        else
          ((float*)Cout)[(size_t)row * Nn + col] = v;
      }
    }
  }
}

// ---------------- flash attention over Pj=[QKV] ----------------------------
// Pj: [4096][3072] bf16, row = n*B+b; Q at col h*64+d, K at +1024, V at +2048.
// Block = (b,h,qb): 64 Q-rows, 4 waves x 16 rows. KV tiles of 64, causal.
__global__ __launch_bounds__(256) void flash_attn_kernel(
    const bf16_t* __restrict__ Pj, bf16_t* __restrict__ AO) {
  __shared__ __align__(16) bf16_t Ks[64 * 72];
  __shared__ __align__(16) bf16_t Vs[64 * 72];
  __shared__ __align__(16) bf16_t Ps[4][16 * 72];
  const int PJP = 3 * HID;
  int tid = threadIdx.x, wave = tid >> 6, lane = tid & 63;
  int c = lane & 15, quad = lane >> 4;
  int bid = blockIdx.x;
  int qb = bid & 31, bh = bid >> 5;
  int h = bh & 15, b = bh >> 4;

  // Q A-fragments (held in registers): m = lane&15 -> seq row, k = quad*8+j
  int i_row = qb * 64 + wave * 16 + c;
  const bf16_t* qg = Pj + (size_t)(i_row * BATCH + b) * PJP + h * HDIM + quad * 8;
  bf16x8 qf0 = *(const bf16x8*)(qg);
  bf16x8 qf1 = *(const bf16x8*)(qg + 32);

  f32x4 o[4] = {};
  float mrow[4], lrow[4];
  #pragma unroll
  for (int r = 0; r < 4; ++r) { mrow[r] = -1e30f; lrow[r] = 0.f; }

  for (int jt = 0; jt <= qb; ++jt) {
    int j0 = jt * 64;
    // stage K (row-major j,d) and V (row-major j,d), 8 bf16 per chunk
    #pragma unroll
    for (int i = 0; i < 2; ++i) {
      int t = tid + i * 256;
      int jr = t >> 3, dc = (t & 7) * 8;
      const bf16_t* kg = Pj + (size_t)((j0 + jr) * BATCH + b) * PJP + HID + h * HDIM + dc;
      *(bf16x8*)(Ks + jr * 72 + dc) = *(const bf16x8*)kg;
      *(bf16x8*)(Vs + jr * 72 + dc) = *(const bf16x8*)(kg + HID);
    }
    __syncthreads();

    // S = Q K^T * scale  (4 col-tiles of 16)
    f32x4 sv[4];
    #pragma unroll
    for (int nt = 0; nt < 4; ++nt) {
      const bf16_t* kr = Ks + (nt * 16 + c) * 72 + quad * 8;
      bf16x8 kb0 = *(const bf16x8*)kr;
      bf16x8 kb1 = *(const bf16x8*)(kr + 32);
      f32x4 s = {};
      s = __builtin_amdgcn_mfma_f32_16x16x32_bf16(qf0, kb0, s, 0, 0, 0);
      s = __builtin_amdgcn_mfma_f32_16x16x32_bf16(qf1, kb1, s, 0, 0, 0);
      s *= ATT_SCALE;
      if (jt == qb) {   // diagonal tile: mask j > i
        #pragma unroll
        for (int r = 0; r < 4; ++r) {
          int i_loc = wave * 16 + quad * 4 + r;
          int j_loc = nt * 16 + c;
          if (j_loc > i_loc) s[r] = -1e30f;
        }
      }
      sv[nt] = s;
    }

    // online softmax (row r lives in the quad's 16 lanes; reduce over bits 0-3)
    float mnew[4], alpha[4];
    #pragma unroll
    for (int r = 0; r < 4; ++r) {
      float mx = fmaxf(fmaxf(sv[0][r], sv[1][r]), fmaxf(sv[2][r], sv[3][r]));
      #pragma unroll
      for (int off = 1; off < 16; off <<= 1)
        mx = fmaxf(mx, __shfl_xor(mx, off));
      mnew[r] = fmaxf(mrow[r], mx);
      alpha[r] = __expf(mrow[r] - mnew[r]);
      mrow[r] = mnew[r];
    }
    #pragma unroll
    for (int nt = 0; nt < 4; ++nt)
      #pragma unroll
      for (int r = 0; r < 4; ++r)
        sv[nt][r] = __expf(sv[nt][r] - mnew[r]);
    #pragma unroll
    for (int r = 0; r < 4; ++r) {
      float s = sv[0][r] + sv[1][r] + sv[2][r] + sv[3][r];
      #pragma unroll
      for (int off = 1; off < 16; off <<= 1)
        s += __shfl_xor(s, off);
      lrow[r] = lrow[r] * alpha[r] + s;
    }
    #pragma unroll
    for (int t = 0; t < 4; ++t)
      #pragma unroll
      for (int r = 0; r < 4; ++r)
        o[t][r] *= alpha[r];

    // P (C-layout) -> LDS -> A-layout fragments (per-wave buffer)
    bf16_t* pw = Ps[wave];
    #pragma unroll
    for (int nt = 0; nt < 4; ++nt)
      #pragma unroll
      for (int r = 0; r < 4; ++r)
        pw[(quad * 4 + r) * 72 + nt * 16 + c] = (bf16_t)sv[nt][r];
    bf16x8 pa0 = *(const bf16x8*)(pw + c * 72 + quad * 8);
    bf16x8 pa1 = *(const bf16x8*)(pw + c * 72 + quad * 8 + 32);

    // O += P V : B-frag B[n=d][k=j] gathered from row-major Vs
    #pragma unroll
    for (int t = 0; t < 4; ++t) {
      bf16x8 vb0, vb1;
      #pragma unroll
      for (int jj = 0; jj < 8; ++jj) {
        vb0[jj] = Vs[(quad * 8 + jj) * 72 + t * 16 + c];
        vb1[jj] = Vs[(quad * 8 + jj + 32) * 72 + t * 16 + c];
      }
      o[t] = __builtin_amdgcn_mfma_f32_16x16x32_bf16(pa0, vb0, o[t], 0, 0, 0);
      o[t] = __builtin_amdgcn_mfma_f32_16x16x32_bf16(pa1, vb1, o[t], 0, 0, 0);
    }
    __syncthreads();
  }

  // epilogue: AO[(n*B+b)][h*64 + d] = O / l
  #pragma unroll
  for (int t = 0; t < 4; ++t) {
    #pragma unroll
    for (int r = 0; r < 4; ++r) {
      int i = qb * 64 + wave * 16 + quad * 4 + r;
      float v = o[t][r] / lrow[r];
      AO[(size_t)(i * BATCH + b) * HID + h * HDIM + t * 16 + c] = (bf16_t)v;
    }
  }
}

extern "C" void kernel_launch(void* const* d_in, const int* in_sizes, int n_in,
                              void* d_out, int out_size, void* d_ws, size_t ws_size,
                              hipStream_t stream) {
  const float* x      = (const float*)d_in[0];   // [2048][2][1024]
  const float* W_proj = (const float*)d_in[1];   // [1024][3072]
  const float* b_proj = (const float*)d_in[2];   // [3072]
  const float* W_out  = (const float*)d_in[3];   // [1024][1024]
  const float* b_out  = (const float*)d_in[4];   // [1024]
  float* out = (float*)d_out;                    // [4096][1024]

  bf16_t* Xb  = (bf16_t*)d_ws;                               // 4096*1024
  bf16_t* Wpt = Xb  + (size_t)NBROW * EMB;                   // 3072*1024
  bf16_t* Wot = Wpt + (size_t)3 * HID * EMB;                 // 1024*1024
  bf16_t* Pj  = Wot + (size_t)HID * EMB;                     // 4096*3072
  bf16_t* AO  = Pj  + (size_t)NBROW * 3 * HID;               // 4096*1024

  // 1. convert x -> bf16 rows (row = n*B+b matches flat layout)
  convert_bf16_kernel<<<(NBROW * EMB) / 1024, 256, 0, stream>>>(x, Xb);
  // 2. W_proj (1024 x 3072) -> Wpt (3072 x 1024);  W_out -> Wot (1024 x 1024)
  transpose_convert_kernel<<<dim3(3 * HID / 32, EMB / 32), 256, 0, stream>>>(
      W_proj, Wpt, EMB, 3 * HID);
  transpose_convert_kernel<<<dim3(EMB / 32, HID / 32), 256, 0, stream>>>(
      W_out, Wot, HID, EMB);
  // 3. QKV projection: Pj = Xb @ Wpt^T + b_proj  (bf16 out)
  gemm_bt_kernel<true><<<dim3(NBROW / 128, 3 * HID / 128), 256, 0, stream>>>(
      Xb, Wpt, b_proj, (void*)Pj, NBROW, 3 * HID, EMB);
  // 4. causal flash attention
  flash_attn_kernel<<<32 * BATCH * NHEAD, 256, 0, stream>>>(Pj, AO);
  // 5. output projection: out = AO @ Wot^T + b_out  (fp32 out)
  gemm_bt_kernel<false><<<dim3(NBROW / 128, EMB / 128), 256, 0, stream>>>(
      AO, Wot, b_out, d_out, NBROW, EMB, HID);
}

// Round 2
// 299.943 us; speedup vs baseline: 1.0685x; 1.0685x over previous
//
#include <hip/hip_runtime.h>
#include <cstdint>
#include <cstddef>

typedef __bf16 bf16_t;
typedef __bf16 bf16x8 __attribute__((ext_vector_type(8)));
typedef __bf16 bf16x4 __attribute__((ext_vector_type(4)));
typedef float f32x4 __attribute__((ext_vector_type(4)));

#define N_SEQ 2048
#define BATCH 2
#define EMB   1024
#define HID   1024
#define NHEAD 16
#define HDIM  64
#define NBROW (N_SEQ * BATCH)   /* 4096 GEMM rows (n*B+b) */
#define ATT_SCALE 0.03125f      /* 1/sqrt(1024) */

static __device__ __forceinline__ void async_copy16(const bf16_t* g, bf16_t* l) {
  __builtin_amdgcn_global_load_lds((const __attribute__((address_space(1))) void*)g,
                                   (__attribute__((address_space(3))) void*)l,
                                   16, 0, 0);
}

// ---------------- elementwise fp32 -> bf16 (4 elems/thread) ----------------
__global__ void convert_bf16_kernel(const float* __restrict__ in,
                                    bf16_t* __restrict__ out) {
  int i = (blockIdx.x * 256 + threadIdx.x) * 4;
  float4 v = *(const float4*)(in + i);
  bf16x4 o;
  o[0] = (bf16_t)v.x; o[1] = (bf16_t)v.y; o[2] = (bf16_t)v.z; o[3] = (bf16_t)v.w;
  *(bf16x4*)(out + i) = o;
}

// ------------- transpose + convert: in R x C fp32 -> out C x R bf16 --------
__global__ void transpose_convert_kernel(const float* __restrict__ in,
                                         bf16_t* __restrict__ out,
                                         int R, int C) {
  __shared__ float tile[32][33];
  int tx = threadIdx.x & 31, ty = threadIdx.x >> 5;   // 32 x 8 threads
  int bc = blockIdx.x * 32, br = blockIdx.y * 32;
  #pragma unroll
  for (int i = 0; i < 32; i += 8)
    tile[ty + i][tx] = in[(size_t)(br + ty + i) * C + bc + tx];
  __syncthreads();
  #pragma unroll
  for (int i = 0; i < 32; i += 8)
    out[(size_t)(bc + ty + i) * R + br + tx] = (bf16_t)tile[tx][ty + i];
}

// ------- V transpose: Pj[n*B+b][2048 + h*64 + d] -> Vt[(b,h)][d][n] --------
// grid: (N/32, 2 (d-halves), 32 (bh)); block 256 = 32x8
__global__ void vt_transpose_kernel(const bf16_t* __restrict__ Pj,
                                    bf16_t* __restrict__ Vt) {
  __shared__ bf16_t tile[32][33];
  int tx = threadIdx.x & 31, ty = threadIdx.x >> 5;
  int n0 = blockIdx.x * 32, d0 = blockIdx.y * 32;
  int bh = blockIdx.z;
  int h = bh & 15, b = bh >> 4;
  const int PJP = 3 * HID;
  #pragma unroll
  for (int i = 0; i < 32; i += 8)
    tile[ty + i][tx] = Pj[(size_t)((n0 + ty + i) * BATCH + b) * PJP + 2 * HID + h * HDIM + d0 + tx];
  __syncthreads();
  #pragma unroll
  for (int i = 0; i < 32; i += 8)
    Vt[(size_t)(bh * HDIM + d0 + ty + i) * N_SEQ + n0 + tx] = tile[tx][ty + i];
}

// ---------------- GEMM: C[M][N] = A[M][K] * Bt[N][K]^T + bias --------------
template <bool OUT_BF16>
__global__ __launch_bounds__(256) void gemm_bt_kernel(
    const bf16_t* __restrict__ A, const bf16_t* __restrict__ Bt,
    const float* __restrict__ bias, void* __restrict__ Cout,
    int M, int Nn, int K) {
  __shared__ __align__(16) bf16_t As[128 * 32];
  __shared__ __align__(16) bf16_t Bs[128 * 32];
  int tid = threadIdx.x;
  int wave = tid >> 6, lane = tid & 63;
  int c = lane & 15, quad = lane >> 4;
  int bm = blockIdx.x * 128;
  int bn = blockIdx.y * 128;
  int wm = (wave & 1) * 64, wn = (wave >> 1) * 64;
  f32x4 acc[4][4] = {};

  for (int kb = 0; kb < K; kb += 32) {
    #pragma unroll
    for (int i = 0; i < 2; ++i) {
      int e = (i * 256 + tid) * 8;           // elem index in 128x32 tile
      int row = e >> 5, kk = e & 31;
      async_copy16(A + (size_t)(bm + row) * K + kb + kk,
                   As + (size_t)(i * 256 + wave * 64) * 8);
      async_copy16(Bt + (size_t)(bn + row) * K + kb + kk,
                   Bs + (size_t)(i * 256 + wave * 64) * 8);
    }
    __syncthreads();
    bf16x8 af[4], bf[4];
    #pragma unroll
    for (int mt = 0; mt < 4; ++mt)
      af[mt] = *(const bf16x8*)(As + (wm + mt * 16 + c) * 32 + quad * 8);
    #pragma unroll
    for (int nt = 0; nt < 4; ++nt)
      bf[nt] = *(const bf16x8*)(Bs + (wn + nt * 16 + c) * 32 + quad * 8);
    #pragma unroll
    for (int mt = 0; mt < 4; ++mt)
      #pragma unroll
      for (int nt = 0; nt < 4; ++nt)
        acc[mt][nt] = __builtin_amdgcn_mfma_f32_16x16x32_bf16(
            af[mt], bf[nt], acc[mt][nt], 0, 0, 0);
    __syncthreads();
  }

  #pragma unroll
  for (int nt = 0; nt < 4; ++nt) {
    int col = bn + wn + nt * 16 + c;
    float bv = bias[col];
    #pragma unroll
    for (int mt = 0; mt < 4; ++mt) {
      #pragma unroll
      for (int r = 0; r < 4; ++r) {
        int row = bm + wm + mt * 16 + quad * 4 + r;   // C layout: row=(lane>>4)*4+reg
        float v = acc[mt][nt][r] + bv;
        if (OUT_BF16)
          ((bf16_t*)Cout)[(size_t)row * Nn + col] = (bf16_t)v;
        else
          ((float*)Cout)[(size_t)row * Nn + col] = v;
      }
    }
  }
}

// ---------------- flash attention ------------------------------------------
// Pj: [4096][3072] bf16 (row = n*B+b); Q at h*64, K at 1024+h*64.
// Vt: [(b,h)][64][2048] bf16 (pre-transposed V).
// Block = (qx, bh): 128 Q-rows (qb = 15-qx, reverse sched), 4 waves x 32 rows.
// KV tiles of 64, causal: jt in [0, 2qb+1].
__global__ __launch_bounds__(256) void flash_attn_kernel(
    const bf16_t* __restrict__ Pj, const bf16_t* __restrict__ Vt,
    bf16_t* __restrict__ AO) {
  __shared__ __align__(16) bf16_t Ks[64 * 72];   // [j][d]
  __shared__ __align__(16) bf16_t Vs[64 * 72];   // [d][j]
  __shared__ __align__(16) bf16_t Ps[4][32 * 72];
  const int PJP = 3 * HID;
  int tid = threadIdx.x, wave = tid >> 6, lane = tid & 63;
  int c = lane & 15, quad = lane >> 4;
  int qb = 15 - blockIdx.x;            // long blocks first
  int bh = blockIdx.y;
  int h = bh & 15, b = bh >> 4;
  int i0 = qb * 128;

  // Q A-fragments: 2 row-groups of 16 per wave
  bf16x8 qf[2][2];
  #pragma unroll
  for (int m = 0; m < 2; ++m) {
    int i_row = i0 + wave * 32 + m * 16 + c;
    const bf16_t* qg = Pj + (size_t)(i_row * BATCH + b) * PJP + h * HDIM + quad * 8;
    qf[m][0] = *(const bf16x8*)(qg);
    qf[m][1] = *(const bf16x8*)(qg + 32);
  }

  f32x4 o[2][4] = {};
  float mrow[2][4], lrow[2][4];
  #pragma unroll
  for (int m = 0; m < 2; ++m)
    #pragma unroll
    for (int r = 0; r < 4; ++r) { mrow[m][r] = -1e30f; lrow[m][r] = 0.f; }

  int njt = 2 * qb + 2;
  for (int jt = 0; jt < njt; ++jt) {
    int j0 = jt * 64;
    // stage K[j][d] from Pj, V[d][j] from Vt (bf16x8 chunks, 2 per thread)
    #pragma unroll
    for (int i = 0; i < 2; ++i) {
      int t = tid + i * 256;
      int jr = t >> 3, dc = (t & 7) * 8;
      *(bf16x8*)(Ks + jr * 72 + dc) =
          *(const bf16x8*)(Pj + (size_t)((j0 + jr) * BATCH + b) * PJP + HID + h * HDIM + dc);
      // reuse jr as d-row, dc as j-col for V
      *(bf16x8*)(Vs + jr * 72 + dc) =
          *(const bf16x8*)(Vt + (size_t)(bh * HDIM + jr) * N_SEQ + j0 + dc);
    }
    __syncthreads();

    // S = Q K^T * scale
    f32x4 sv[2][4];
    #pragma unroll
    for (int nt = 0; nt < 4; ++nt) {
      const bf16_t* kr = Ks + (nt * 16 + c) * 72 + quad * 8;
      bf16x8 kb0 = *(const bf16x8*)kr;
      bf16x8 kb1 = *(const bf16x8*)(kr + 32);
      #pragma unroll
      for (int m = 0; m < 2; ++m) {
        f32x4 s = {};
        s = __builtin_amdgcn_mfma_f32_16x16x32_bf16(qf[m][0], kb0, s, 0, 0, 0);
        s = __builtin_amdgcn_mfma_f32_16x16x32_bf16(qf[m][1], kb1, s, 0, 0, 0);
        sv[m][nt] = s * ATT_SCALE;
      }
    }
    if (jt >= 2 * qb) {   // diagonal-region tiles: mask j > i
      #pragma unroll
      for (int m = 0; m < 2; ++m)
        #pragma unroll
        for (int nt = 0; nt < 4; ++nt)
          #pragma unroll
          for (int r = 0; r < 4; ++r) {
            int ig = i0 + wave * 32 + m * 16 + quad * 4 + r;
            int jg = j0 + nt * 16 + c;
            if (jg > ig) sv[m][nt][r] = -1e30f;
          }
    }

    // online softmax per row-group
    #pragma unroll
    for (int m = 0; m < 2; ++m) {
      float mnew[4], alpha[4];
      #pragma unroll
      for (int r = 0; r < 4; ++r) {
        float mx = fmaxf(fmaxf(sv[m][0][r], sv[m][1][r]), fmaxf(sv[m][2][r], sv[m][3][r]));
        #pragma unroll
        for (int off = 1; off < 16; off <<= 1)
          mx = fmaxf(mx, __shfl_xor(mx, off));
        mnew[r] = fmaxf(mrow[m][r], mx);
        alpha[r] = __expf(mrow[m][r] - mnew[r]);
        mrow[m][r] = mnew[r];
      }
      #pragma unroll
      for (int nt = 0; nt < 4; ++nt)
        #pragma unroll
        for (int r = 0; r < 4; ++r)
          sv[m][nt][r] = __expf(sv[m][nt][r] - mnew[r]);
      #pragma unroll
      for (int r = 0; r < 4; ++r) {
        float s = sv[m][0][r] + sv[m][1][r] + sv[m][2][r] + sv[m][3][r];
        #pragma unroll
        for (int off = 1; off < 16; off <<= 1)
          s += __shfl_xor(s, off);
        lrow[m][r] = lrow[m][r] * alpha[r] + s;
      }
      #pragma unroll
      for (int t = 0; t < 4; ++t)
        #pragma unroll
        for (int r = 0; r < 4; ++r)
          o[m][t][r] *= alpha[r];
    }

    // P (C-layout) -> LDS -> A-layout fragments (per-wave buffer)
    bf16_t* pw = Ps[wave];
    #pragma unroll
    for (int m = 0; m < 2; ++m)
      #pragma unroll
      for (int nt = 0; nt < 4; ++nt)
        #pragma unroll
        for (int r = 0; r < 4; ++r)
          pw[(m * 16 + quad * 4 + r) * 72 + nt * 16 + c] = (bf16_t)sv[m][nt][r];

    bf16x8 pa[2][2];
    #pragma unroll
    for (int m = 0; m < 2; ++m) {
      const bf16_t* pr = pw + (m * 16 + c) * 72 + quad * 8;
      pa[m][0] = *(const bf16x8*)pr;
      pa[m][1] = *(const bf16x8*)(pr + 32);
    }

    // O += P V : B-frags are vectorized rows of Vs[d][j]
    #pragma unroll
    for (int t = 0; t < 4; ++t) {
      const bf16_t* vr = Vs + (t * 16 + c) * 72 + quad * 8;
      bf16x8 vb0 = *(const bf16x8*)vr;
      bf16x8 vb1 = *(const bf16x8*)(vr + 32);
      #pragma unroll
      for (int m = 0; m < 2; ++m) {
        o[m][t] = __builtin_amdgcn_mfma_f32_16x16x32_bf16(pa[m][0], vb0, o[m][t], 0, 0, 0);
        o[m][t] = __builtin_amdgcn_mfma_f32_16x16x32_bf16(pa[m][1], vb1, o[m][t], 0, 0, 0);
      }
    }
    __syncthreads();
  }

  // epilogue: AO[(n*B+b)][h*64 + d] = O / l
  #pragma unroll
  for (int m = 0; m < 2; ++m)
    #pragma unroll
    for (int t = 0; t < 4; ++t)
      #pragma unroll
      for (int r = 0; r < 4; ++r) {
        int i = i0 + wave * 32 + m * 16 + quad * 4 + r;
        float v = o[m][t][r] / lrow[m][r];
        AO[(size_t)(i * BATCH + b) * HID + h * HDIM + t * 16 + c] = (bf16_t)v;
      }
}

extern "C" void kernel_launch(void* const* d_in, const int* in_sizes, int n_in,
                              void* d_out, int out_size, void* d_ws, size_t ws_size,
                              hipStream_t stream) {
  const float* x      = (const float*)d_in[0];   // [2048][2][1024]
  const float* W_proj = (const float*)d_in[1];   // [1024][3072]
  const float* b_proj = (const float*)d_in[2];   // [3072]
  const float* W_out  = (const float*)d_in[3];   // [1024][1024]
  const float* b_out  = (const float*)d_in[4];   // [1024]

  bf16_t* Xb  = (bf16_t*)d_ws;                               // 4096*1024
  bf16_t* Wpt = Xb  + (size_t)NBROW * EMB;                   // 3072*1024
  bf16_t* Wot = Wpt + (size_t)3 * HID * EMB;                 // 1024*1024
  bf16_t* Pj  = Wot + (size_t)HID * EMB;                     // 4096*3072
  bf16_t* AO  = Pj  + (size_t)NBROW * 3 * HID;               // 4096*1024
  bf16_t* Vt  = AO  + (size_t)NBROW * HID;                   // 32*64*2048

  convert_bf16_kernel<<<(NBROW * EMB) / 1024, 256, 0, stream>>>(x, Xb);
  transpose_convert_kernel<<<dim3(3 * HID / 32, EMB / 32), 256, 0, stream>>>(
      W_proj, Wpt, EMB, 3 * HID);
  transpose_convert_kernel<<<dim3(EMB / 32, HID / 32), 256, 0, stream>>>(
      W_out, Wot, HID, EMB);
  gemm_bt_kernel<true><<<dim3(NBROW / 128, 3 * HID / 128), 256, 0, stream>>>(
      Xb, Wpt, b_proj, (void*)Pj, NBROW, 3 * HID, EMB);
  vt_transpose_kernel<<<dim3(N_SEQ / 32, HDIM / 32, BATCH * NHEAD), 256, 0, stream>>>(
      Pj, Vt);
  flash_attn_kernel<<<dim3(16, BATCH * NHEAD), 256, 0, stream>>>(Pj, Vt, AO);
  gemm_bt_kernel<false><<<dim3(NBROW / 128, EMB / 128), 256, 0, stream>>>(
      AO, Wot, b_out, d_out, NBROW, EMB, HID);
}

// Round 4
// 209.158 us; speedup vs baseline: 1.5323x; 1.4341x over previous
//
#include <hip/hip_runtime.h>
#include <cstdint>
#include <cstddef>

typedef __bf16 bf16_t;
typedef __bf16 bf16x8 __attribute__((ext_vector_type(8)));
typedef __bf16 bf16x4 __attribute__((ext_vector_type(4)));
typedef float f32x4 __attribute__((ext_vector_type(4)));

#define N_SEQ 2048
#define BATCH 2
#define EMB   1024
#define HID   1024
#define NHEAD 16
#define HDIM  64
#define NBROW (N_SEQ * BATCH)   /* 4096 GEMM rows (n*B+b) */
#define ATT_SCALE 0.03125f      /* 1/sqrt(1024) */
#define ATT_SCALE2 (0.03125f * 1.44269504f)  /* scale * log2(e), for exp2 domain */

#define EXP2F(x) __builtin_amdgcn_exp2f(x)   /* __exp2f collides with glibc macro */

static __device__ __forceinline__ void async_copy16(const bf16_t* g, bf16_t* l) {
  __builtin_amdgcn_global_load_lds((const __attribute__((address_space(1))) void*)g,
                                   (__attribute__((address_space(3))) void*)l,
                                   16, 0, 0);
}

// ---------------- elementwise fp32 -> bf16 (4 elems/thread) ----------------
__global__ void convert_bf16_kernel(const float* __restrict__ in,
                                    bf16_t* __restrict__ out) {
  int i = (blockIdx.x * 256 + threadIdx.x) * 4;
  float4 v = *(const float4*)(in + i);
  bf16x4 o;
  o[0] = (bf16_t)v.x; o[1] = (bf16_t)v.y; o[2] = (bf16_t)v.z; o[3] = (bf16_t)v.w;
  *(bf16x4*)(out + i) = o;
}

// ------------- transpose + convert: in R x C fp32 -> out C x R bf16 --------
__global__ void transpose_convert_kernel(const float* __restrict__ in,
                                         bf16_t* __restrict__ out,
                                         int R, int C) {
  __shared__ float tile[32][33];
  int tx = threadIdx.x & 31, ty = threadIdx.x >> 5;   // 32 x 8 threads
  int bc = blockIdx.x * 32, br = blockIdx.y * 32;
  #pragma unroll
  for (int i = 0; i < 32; i += 8)
    tile[ty + i][tx] = in[(size_t)(br + ty + i) * C + bc + tx];
  __syncthreads();
  #pragma unroll
  for (int i = 0; i < 32; i += 8)
    out[(size_t)(bc + ty + i) * R + br + tx] = (bf16_t)tile[tx][ty + i];
}

// ------- V transpose: Pj[n*B+b][2048 + h*64 + d] -> Vt[(b,h)][d][n] --------
__global__ void vt_transpose_kernel(const bf16_t* __restrict__ Pj,
                                    bf16_t* __restrict__ Vt) {
  __shared__ bf16_t tile[32][33];
  int tx = threadIdx.x & 31, ty = threadIdx.x >> 5;
  int n0 = blockIdx.x * 32, d0 = blockIdx.y * 32;
  int bh = blockIdx.z;
  int h = bh & 15, b = bh >> 4;
  const int PJP = 3 * HID;
  #pragma unroll
  for (int i = 0; i < 32; i += 8)
    tile[ty + i][tx] = Pj[(size_t)((n0 + ty + i) * BATCH + b) * PJP + 2 * HID + h * HDIM + d0 + tx];
  __syncthreads();
  #pragma unroll
  for (int i = 0; i < 32; i += 8)
    Vt[(size_t)(bh * HDIM + d0 + ty + i) * N_SEQ + n0 + tx] = tile[tx][ty + i];
}

// ---------------- GEMM: C[M][N] = A[M][K] * Bt[N][K]^T + bias --------------
template <bool OUT_BF16>
__global__ __launch_bounds__(256) void gemm_bt_kernel(
    const bf16_t* __restrict__ A, const bf16_t* __restrict__ Bt,
    const float* __restrict__ bias, void* __restrict__ Cout,
    int M, int Nn, int K) {
  __shared__ __align__(16) bf16_t As[128 * 32];
  __shared__ __align__(16) bf16_t Bs[128 * 32];
  int tid = threadIdx.x;
  int wave = tid >> 6, lane = tid & 63;
  int c = lane & 15, quad = lane >> 4;
  int bm = blockIdx.x * 128;
  int bn = blockIdx.y * 128;
  int wm = (wave & 1) * 64, wn = (wave >> 1) * 64;
  f32x4 acc[4][4] = {};

  for (int kb = 0; kb < K; kb += 32) {
    #pragma unroll
    for (int i = 0; i < 2; ++i) {
      int e = (i * 256 + tid) * 8;           // elem index in 128x32 tile
      int row = e >> 5, kk = e & 31;
      async_copy16(A + (size_t)(bm + row) * K + kb + kk,
                   As + (size_t)(i * 256 + wave * 64) * 8);
      async_copy16(Bt + (size_t)(bn + row) * K + kb + kk,
                   Bs + (size_t)(i * 256 + wave * 64) * 8);
    }
    __syncthreads();
    bf16x8 af[4], bf[4];
    #pragma unroll
    for (int mt = 0; mt < 4; ++mt)
      af[mt] = *(const bf16x8*)(As + (wm + mt * 16 + c) * 32 + quad * 8);
    #pragma unroll
    for (int nt = 0; nt < 4; ++nt)
      bf[nt] = *(const bf16x8*)(Bs + (wn + nt * 16 + c) * 32 + quad * 8);
    #pragma unroll
    for (int mt = 0; mt < 4; ++mt)
      #pragma unroll
      for (int nt = 0; nt < 4; ++nt)
        acc[mt][nt] = __builtin_amdgcn_mfma_f32_16x16x32_bf16(
            af[mt], bf[nt], acc[mt][nt], 0, 0, 0);
    __syncthreads();
  }

  #pragma unroll
  for (int nt = 0; nt < 4; ++nt) {
    int col = bn + wn + nt * 16 + c;
    float bv = bias[col];
    #pragma unroll
    for (int mt = 0; mt < 4; ++mt) {
      #pragma unroll
      for (int r = 0; r < 4; ++r) {
        int row = bm + wm + mt * 16 + quad * 4 + r;   // C layout: row=(lane>>4)*4+reg
        float v = acc[mt][nt][r] + bv;
        if (OUT_BF16)
          ((bf16_t*)Cout)[(size_t)row * Nn + col] = (bf16_t)v;
        else
          ((float*)Cout)[(size_t)row * Nn + col] = v;
      }
    }
  }
}

// ---------------- flash attention ------------------------------------------
// Pj: [4096][3072] bf16 (row = n*B+b); Q at h*64, K at 1024+h*64.
// Vt: [(b,h)][64][2048] bf16 (pre-transposed V).
// 512 threads = 8 waves x 16 Q-rows = 128-row Q tile. KV tiles of 64.
// Transposed-S: S^T = K·Q^T so softmax rows are per-lane (col = lane&15).
// Single barrier/iter: register prefetch + double-buffered K/V LDS.
__global__ __launch_bounds__(512, 4) void flash_attn_kernel(
    const bf16_t* __restrict__ Pj, const bf16_t* __restrict__ Vt,
    bf16_t* __restrict__ AO) {
  __shared__ __align__(16) bf16_t Ks[2][64 * 72];   // [j][d]
  __shared__ __align__(16) bf16_t Vs[2][64 * 72];   // [d][j]
  __shared__ __align__(16) bf16_t Ps[8][16 * 72];   // per-wave P[i][j]
  const int PJP = 3 * HID;
  int tid = threadIdx.x, wave = tid >> 6, lane = tid & 63;
  int c = lane & 15, quad = lane >> 4;
  // pair-balanced schedule: blocks i and i+256 sum to 36 tiles
  int bid = blockIdx.x;
  int qb = (bid < 256) ? (15 - (bid >> 5)) : ((bid - 256) >> 5);
  int bh = bid & 31;
  int h = bh & 15, b = bh >> 4;
  int i0 = qb * 128;

  // Q fragment (used as B operand: lane holds Q[i=c][d=quad*8+jj])
  int i_row = i0 + wave * 16 + c;
  const bf16_t* qg = Pj + (size_t)(i_row * BATCH + b) * PJP + h * HDIM + quad * 8;
  bf16x8 qf0 = *(const bf16x8*)(qg);
  bf16x8 qf1 = *(const bf16x8*)(qg + 32);

  f32x4 o[4] = {};
  float mrow = -1e30f, lrow = 0.f;   // per-lane: row i = c (replicated across quads)

  // staging: thread covers 16B of K-tile and 16B of V-tile
  int jr = tid >> 3, dcol = (tid & 7) * 8;
  const bf16_t* kg0 = Pj + (size_t)b * PJP + HID + h * HDIM + dcol;   // + j*BATCH*PJP
  const bf16_t* vg0 = Vt + (size_t)(bh * HDIM + jr) * N_SEQ + dcol;   // + j0

  int njt = 2 * qb + 2;
  bf16x8 kreg = *(const bf16x8*)(kg0 + (size_t)jr * BATCH * PJP);
  bf16x8 vreg = *(const bf16x8*)(vg0);

  for (int jt = 0; jt < njt; ++jt) {
    bf16_t* ks = Ks[jt & 1];
    bf16_t* vs = Vs[jt & 1];
    *(bf16x8*)(ks + jr * 72 + dcol) = kreg;
    *(bf16x8*)(vs + jr * 72 + dcol) = vreg;
    __syncthreads();
    if (jt + 1 < njt) {          // prefetch next tile into regs (hidden by compute)
      int j0n = (jt + 1) * 64;
      kreg = *(const bf16x8*)(kg0 + (size_t)(j0n + jr) * BATCH * PJP);
      vreg = *(const bf16x8*)(vg0 + j0n);
    }

    // S^T[j][i] = K Q^T, scaled into exp2 domain
    f32x4 st[4];
    #pragma unroll
    for (int mt = 0; mt < 4; ++mt) {
      const bf16_t* kr = ks + (mt * 16 + c) * 72 + quad * 8;
      bf16x8 ka0 = *(const bf16x8*)kr;
      bf16x8 ka1 = *(const bf16x8*)(kr + 32);
      f32x4 s = {};
      s = __builtin_amdgcn_mfma_f32_16x16x32_bf16(ka0, qf0, s, 0, 0, 0);
      s = __builtin_amdgcn_mfma_f32_16x16x32_bf16(ka1, qf1, s, 0, 0, 0);
      st[mt] = s * ATT_SCALE2;
    }
    if (jt >= 2 * qb) {   // diagonal region: mask j > i
      int j0 = jt * 64;
      int ig = i0 + wave * 16 + c;
      #pragma unroll
      for (int mt = 0; mt < 4; ++mt)
        #pragma unroll
        for (int r = 0; r < 4; ++r)
          if (j0 + mt * 16 + quad * 4 + r > ig) st[mt][r] = -1e30f;
    }

    // online softmax over j (16 in-lane values + 2 quad shuffles)
    float mx = st[0][0];
    #pragma unroll
    for (int mt = 0; mt < 4; ++mt)
      #pragma unroll
      for (int r = 0; r < 4; ++r) mx = fmaxf(mx, st[mt][r]);
    mx = fmaxf(mx, __shfl_xor(mx, 16));
    mx = fmaxf(mx, __shfl_xor(mx, 32));
    float mnew = fmaxf(mrow, mx);
    float alpha = EXP2F(mrow - mnew);
    mrow = mnew;
    float sum = 0.f;
    #pragma unroll
    for (int mt = 0; mt < 4; ++mt)
      #pragma unroll
      for (int r = 0; r < 4; ++r) {
        st[mt][r] = EXP2F(st[mt][r] - mnew);
        sum += st[mt][r];
      }
    sum += __shfl_xor(sum, 16);
    sum += __shfl_xor(sum, 32);
    lrow = lrow * alpha + sum;

    // rescale O (broadcast alpha from lane layout to row layout)
    float ar[4];
    #pragma unroll
    for (int r = 0; r < 4; ++r) ar[r] = __shfl(alpha, quad * 4 + r);
    #pragma unroll
    for (int nt = 0; nt < 4; ++nt)
      #pragma unroll
      for (int r = 0; r < 4; ++r) o[nt][r] *= ar[r];

    // store P[i][j] (transposed store of S^T C-frags: 4x 8B vector writes)
    bf16_t* pw = Ps[wave];
    #pragma unroll
    for (int mt = 0; mt < 4; ++mt) {
      bf16x4 pv;
      #pragma unroll
      for (int r = 0; r < 4; ++r) pv[r] = (bf16_t)st[mt][r];
      *(bf16x4*)(pw + c * 72 + mt * 16 + quad * 4) = pv;
    }
    const bf16_t* pr = pw + c * 72 + quad * 8;
    bf16x8 pa0 = *(const bf16x8*)pr;
    bf16x8 pa1 = *(const bf16x8*)(pr + 32);

    // O += P V (V B-frags are vectorized rows of Vs[d][j])
    #pragma unroll
    for (int nt = 0; nt < 4; ++nt) {
      const bf16_t* vr = vs + (nt * 16 + c) * 72 + quad * 8;
      bf16x8 vb0 = *(const bf16x8*)vr;
      bf16x8 vb1 = *(const bf16x8*)(vr + 32);
      o[nt] = __builtin_amdgcn_mfma_f32_16x16x32_bf16(pa0, vb0, o[nt], 0, 0, 0);
      o[nt] = __builtin_amdgcn_mfma_f32_16x16x32_bf16(pa1, vb1, o[nt], 0, 0, 0);
    }
    // no second barrier: next iter writes the other LDS buffer
  }

  // epilogue: AO[i][h*64+d] = O / l  (broadcast l to row layout)
  float lr[4];
  #pragma unroll
  for (int r = 0; r < 4; ++r) lr[r] = __shfl(lrow, quad * 4 + r);
  #pragma unroll
  for (int nt = 0; nt < 4; ++nt)
    #pragma unroll
    for (int r = 0; r < 4; ++r) {
      int i = i0 + wave * 16 + quad * 4 + r;
      AO[(size_t)(i * BATCH + b) * HID + h * HDIM + nt * 16 + c] =
          (bf16_t)(o[nt][r] / lr[r]);
    }
}

extern "C" void kernel_launch(void* const* d_in, const int* in_sizes, int n_in,
                              void* d_out, int out_size, void* d_ws, size_t ws_size,
                              hipStream_t stream) {
  const float* x      = (const float*)d_in[0];   // [2048][2][1024]
  const float* W_proj = (const float*)d_in[1];   // [1024][3072]
  const float* b_proj = (const float*)d_in[2];   // [3072]
  const float* W_out  = (const float*)d_in[3];   // [1024][1024]
  const float* b_out  = (const float*)d_in[4];   // [1024]

  bf16_t* Xb  = (bf16_t*)d_ws;                               // 4096*1024
  bf16_t* Wpt = Xb  + (size_t)NBROW * EMB;                   // 3072*1024
  bf16_t* Wot = Wpt + (size_t)3 * HID * EMB;                 // 1024*1024
  bf16_t* Pj  = Wot + (size_t)HID * EMB;                     // 4096*3072
  bf16_t* AO  = Pj  + (size_t)NBROW * 3 * HID;               // 4096*1024
  bf16_t* Vt  = AO  + (size_t)NBROW * HID;                   // 32*64*2048

  convert_bf16_kernel<<<(NBROW * EMB) / 1024, 256, 0, stream>>>(x, Xb);
  transpose_convert_kernel<<<dim3(3 * HID / 32, EMB / 32), 256, 0, stream>>>(
      W_proj, Wpt, EMB, 3 * HID);
  transpose_convert_kernel<<<dim3(EMB / 32, HID / 32), 256, 0, stream>>>(
      W_out, Wot, HID, EMB);
  gemm_bt_kernel<true><<<dim3(NBROW / 128, 3 * HID / 128), 256, 0, stream>>>(
      Xb, Wpt, b_proj, (void*)Pj, NBROW, 3 * HID, EMB);
  vt_transpose_kernel<<<dim3(N_SEQ / 32, HDIM / 32, BATCH * NHEAD), 256, 0, stream>>>(
      Pj, Vt);
  flash_attn_kernel<<<512, 512, 0, stream>>>(Pj, Vt, AO);
  gemm_bt_kernel<false><<<dim3(NBROW / 128, EMB / 128), 256, 0, stream>>>(
      AO, Wot, b_out, d_out, NBROW, EMB, HID);
}

// Round 5
// 196.780 us; speedup vs baseline: 1.6287x; 1.0629x over previous
//
#include <hip/hip_runtime.h>
#include <cstdint>
#include <cstddef>

typedef __bf16 bf16_t;
typedef __bf16 bf16x8 __attribute__((ext_vector_type(8)));
typedef __bf16 bf16x4 __attribute__((ext_vector_type(4)));
typedef float f32x4 __attribute__((ext_vector_type(4)));

#define N_SEQ 2048
#define BATCH 2
#define EMB   1024
#define HID   1024
#define NHEAD 16
#define HDIM  64
#define NBROW (N_SEQ * BATCH)   /* 4096 GEMM rows (n*B+b) */
#define ATT_SCALE 0.03125f      /* 1/sqrt(1024) */
#define ATT_SCALE2 (0.03125f * 1.44269504f)  /* scale * log2(e), for exp2 domain */

#define EXP2F(x) __builtin_amdgcn_exp2f(x)   /* __exp2f collides with glibc macro */

static __device__ __forceinline__ void async_copy16(const bf16_t* g, bf16_t* l) {
  __builtin_amdgcn_global_load_lds((const __attribute__((address_space(1))) void*)g,
                                   (__attribute__((address_space(3))) void*)l,
                                   16, 0, 0);
}

// ---------------- elementwise fp32 -> bf16 (4 elems/thread) ----------------
__global__ void convert_bf16_kernel(const float* __restrict__ in,
                                    bf16_t* __restrict__ out) {
  int i = (blockIdx.x * 256 + threadIdx.x) * 4;
  float4 v = *(const float4*)(in + i);
  bf16x4 o;
  o[0] = (bf16_t)v.x; o[1] = (bf16_t)v.y; o[2] = (bf16_t)v.z; o[3] = (bf16_t)v.w;
  *(bf16x4*)(out + i) = o;
}

// ------------- transpose + convert: in R x C fp32 -> out C x R bf16 --------
__global__ void transpose_convert_kernel(const float* __restrict__ in,
                                         bf16_t* __restrict__ out,
                                         int R, int C) {
  __shared__ float tile[32][33];
  int tx = threadIdx.x & 31, ty = threadIdx.x >> 5;   // 32 x 8 threads
  int bc = blockIdx.x * 32, br = blockIdx.y * 32;
  #pragma unroll
  for (int i = 0; i < 32; i += 8)
    tile[ty + i][tx] = in[(size_t)(br + ty + i) * C + bc + tx];
  __syncthreads();
  #pragma unroll
  for (int i = 0; i < 32; i += 8)
    out[(size_t)(bc + ty + i) * R + br + tx] = (bf16_t)tile[tx][ty + i];
}

// ------- V transpose: Pj[n*B+b][2048 + h*64 + d] -> Vt[(b,h)][d][n] --------
__global__ void vt_transpose_kernel(const bf16_t* __restrict__ Pj,
                                    bf16_t* __restrict__ Vt) {
  __shared__ bf16_t tile[32][33];
  int tx = threadIdx.x & 31, ty = threadIdx.x >> 5;
  int n0 = blockIdx.x * 32, d0 = blockIdx.y * 32;
  int bh = blockIdx.z;
  int h = bh & 15, b = bh >> 4;
  const int PJP = 3 * HID;
  #pragma unroll
  for (int i = 0; i < 32; i += 8)
    tile[ty + i][tx] = Pj[(size_t)((n0 + ty + i) * BATCH + b) * PJP + 2 * HID + h * HDIM + d0 + tx];
  __syncthreads();
  #pragma unroll
  for (int i = 0; i < 32; i += 8)
    Vt[(size_t)(bh * HDIM + d0 + ty + i) * N_SEQ + n0 + tx] = tile[tx][ty + i];
}

// ---------------- GEMM: C[M][N] = A[M][K] * Bt[N][K]^T + bias --------------
// BM=128, BN templated (64 or 128). 4 waves in 2x2; wave tile 64 x BN/2.
// BN=64 shrinks acc to 2x4xf32x4 and multiplies grid blocks/CU for
// latency hiding (QKV: 1536 blocks = 6/CU; out-proj: 512 = 2/CU).
template <int BN, bool OUT_BF16>
__global__ __launch_bounds__(256) void gemm_bt_kernel(
    const bf16_t* __restrict__ A, const bf16_t* __restrict__ Bt,
    const float* __restrict__ bias, void* __restrict__ Cout,
    int M, int Nn, int K) {
  constexpr int NT = BN / 32;              // 16-col MFMA tiles per wave
  __shared__ __align__(16) bf16_t As[128 * 32];
  __shared__ __align__(16) bf16_t Bs[BN * 32];
  int tid = threadIdx.x;
  int wave = tid >> 6, lane = tid & 63;
  int c = lane & 15, quad = lane >> 4;
  int bm = blockIdx.x * 128;
  int bn = blockIdx.y * BN;
  int wm = (wave & 1) * 64, wn = (wave >> 1) * (BN / 2);
  f32x4 acc[4][NT] = {};

  for (int kb = 0; kb < K; kb += 32) {
    #pragma unroll
    for (int i = 0; i < 2; ++i) {
      int e = (i * 256 + tid) * 8;           // elem index in 128x32 A tile
      int row = e >> 5, kk = e & 31;
      async_copy16(A + (size_t)(bm + row) * K + kb + kk,
                   As + (size_t)(i * 256 + wave * 64) * 8);
    }
    #pragma unroll
    for (int i = 0; i < BN / 64; ++i) {
      int e = (i * 256 + tid) * 8;           // elem index in BNx32 B tile
      int row = e >> 5, kk = e & 31;
      async_copy16(Bt + (size_t)(bn + row) * K + kb + kk,
                   Bs + (size_t)(i * 256 + wave * 64) * 8);
    }
    __syncthreads();
    bf16x8 af[4], bf[NT];
    #pragma unroll
    for (int mt = 0; mt < 4; ++mt)
      af[mt] = *(const bf16x8*)(As + (wm + mt * 16 + c) * 32 + quad * 8);
    #pragma unroll
    for (int nt = 0; nt < NT; ++nt)
      bf[nt] = *(const bf16x8*)(Bs + (wn + nt * 16 + c) * 32 + quad * 8);
    #pragma unroll
    for (int mt = 0; mt < 4; ++mt)
      #pragma unroll
      for (int nt = 0; nt < NT; ++nt)
        acc[mt][nt] = __builtin_amdgcn_mfma_f32_16x16x32_bf16(
            af[mt], bf[nt], acc[mt][nt], 0, 0, 0);
    __syncthreads();
  }

  #pragma unroll
  for (int nt = 0; nt < NT; ++nt) {
    int col = bn + wn + nt * 16 + c;
    float bv = bias[col];
    #pragma unroll
    for (int mt = 0; mt < 4; ++mt) {
      #pragma unroll
      for (int r = 0; r < 4; ++r) {
        int row = bm + wm + mt * 16 + quad * 4 + r;   // C layout: row=(lane>>4)*4+reg
        float v = acc[mt][nt][r] + bv;
        if (OUT_BF16)
          ((bf16_t*)Cout)[(size_t)row * Nn + col] = (bf16_t)v;
        else
          ((float*)Cout)[(size_t)row * Nn + col] = v;
      }
    }
  }
}

// ---------------- flash attention ------------------------------------------
// Pj: [4096][3072] bf16 (row = n*B+b); Q at h*64, K at 1024+h*64.
// Vt: [(b,h)][64][2048] bf16 (pre-transposed V).
// 512 threads = 8 waves x 16 Q-rows = 128-row Q tile. KV tiles of 64.
// Transposed-S: S^T = K·Q^T so softmax rows are per-lane (col = lane&15).
// Single barrier/iter: register prefetch + double-buffered K/V LDS.
__global__ __launch_bounds__(512, 4) void flash_attn_kernel(
    const bf16_t* __restrict__ Pj, const bf16_t* __restrict__ Vt,
    bf16_t* __restrict__ AO) {
  __shared__ __align__(16) bf16_t Ks[2][64 * 72];   // [j][d]
  __shared__ __align__(16) bf16_t Vs[2][64 * 72];   // [d][j]
  __shared__ __align__(16) bf16_t Ps[8][16 * 72];   // per-wave P[i][j]
  const int PJP = 3 * HID;
  int tid = threadIdx.x, wave = tid >> 6, lane = tid & 63;
  int c = lane & 15, quad = lane >> 4;
  // pair-balanced schedule: blocks i and i+256 sum to 36 tiles
  int bid = blockIdx.x;
  int qb = (bid < 256) ? (15 - (bid >> 5)) : ((bid - 256) >> 5);
  int bh = bid & 31;
  int h = bh & 15, b = bh >> 4;
  int i0 = qb * 128;

  // Q fragment (used as B operand: lane holds Q[i=c][d=quad*8+jj])
  int i_row = i0 + wave * 16 + c;
  const bf16_t* qg = Pj + (size_t)(i_row * BATCH + b) * PJP + h * HDIM + quad * 8;
  bf16x8 qf0 = *(const bf16x8*)(qg);
  bf16x8 qf1 = *(const bf16x8*)(qg + 32);

  f32x4 o[4] = {};
  float mrow = -1e30f, lrow = 0.f;   // per-lane: row i = c (replicated across quads)

  // staging: thread covers 16B of K-tile and 16B of V-tile
  int jr = tid >> 3, dcol = (tid & 7) * 8;
  const bf16_t* kg0 = Pj + (size_t)b * PJP + HID + h * HDIM + dcol;   // + j*BATCH*PJP
  const bf16_t* vg0 = Vt + (size_t)(bh * HDIM + jr) * N_SEQ + dcol;   // + j0

  int njt = 2 * qb + 2;
  bf16x8 kreg = *(const bf16x8*)(kg0 + (size_t)jr * BATCH * PJP);
  bf16x8 vreg = *(const bf16x8*)(vg0);

  for (int jt = 0; jt < njt; ++jt) {
    bf16_t* ks = Ks[jt & 1];
    bf16_t* vs = Vs[jt & 1];
    *(bf16x8*)(ks + jr * 72 + dcol) = kreg;
    *(bf16x8*)(vs + jr * 72 + dcol) = vreg;
    __syncthreads();
    if (jt + 1 < njt) {          // prefetch next tile into regs (hidden by compute)
      int j0n = (jt + 1) * 64;
      kreg = *(const bf16x8*)(kg0 + (size_t)(j0n + jr) * BATCH * PJP);
      vreg = *(const bf16x8*)(vg0 + j0n);
    }

    // S^T[j][i] = K Q^T, scaled into exp2 domain
    f32x4 st[4];
    #pragma unroll
    for (int mt = 0; mt < 4; ++mt) {
      const bf16_t* kr = ks + (mt * 16 + c) * 72 + quad * 8;
      bf16x8 ka0 = *(const bf16x8*)kr;
      bf16x8 ka1 = *(const bf16x8*)(kr + 32);
      f32x4 s = {};
      s = __builtin_amdgcn_mfma_f32_16x16x32_bf16(ka0, qf0, s, 0, 0, 0);
      s = __builtin_amdgcn_mfma_f32_16x16x32_bf16(ka1, qf1, s, 0, 0, 0);
      st[mt] = s * ATT_SCALE2;
    }
    if (jt >= 2 * qb) {   // diagonal region: mask j > i
      int j0 = jt * 64;
      int ig = i0 + wave * 16 + c;
      #pragma unroll
      for (int mt = 0; mt < 4; ++mt)
        #pragma unroll
        for (int r = 0; r < 4; ++r)
          if (j0 + mt * 16 + quad * 4 + r > ig) st[mt][r] = -1e30f;
    }

    // online softmax over j (16 in-lane values + 2 quad shuffles)
    float mx = st[0][0];
    #pragma unroll
    for (int mt = 0; mt < 4; ++mt)
      #pragma unroll
      for (int r = 0; r < 4; ++r) mx = fmaxf(mx, st[mt][r]);
    mx = fmaxf(mx, __shfl_xor(mx, 16));
    mx = fmaxf(mx, __shfl_xor(mx, 32));
    float mnew = fmaxf(mrow, mx);
    float alpha = EXP2F(mrow - mnew);
    mrow = mnew;
    float sum = 0.f;
    #pragma unroll
    for (int mt = 0; mt < 4; ++mt)
      #pragma unroll
      for (int r = 0; r < 4; ++r) {
        st[mt][r] = EXP2F(st[mt][r] - mnew);
        sum += st[mt][r];
      }
    sum += __shfl_xor(sum, 16);
    sum += __shfl_xor(sum, 32);
    lrow = lrow * alpha + sum;

    // rescale O (broadcast alpha from lane layout to row layout)
    float ar[4];
    #pragma unroll
    for (int r = 0; r < 4; ++r) ar[r] = __shfl(alpha, quad * 4 + r);
    #pragma unroll
    for (int nt = 0; nt < 4; ++nt)
      #pragma unroll
      for (int r = 0; r < 4; ++r) o[nt][r] *= ar[r];

    // store P[i][j] (transposed store of S^T C-frags: 4x 8B vector writes)
    bf16_t* pw = Ps[wave];
    #pragma unroll
    for (int mt = 0; mt < 4; ++mt) {
      bf16x4 pv;
      #pragma unroll
      for (int r = 0; r < 4; ++r) pv[r] = (bf16_t)st[mt][r];
      *(bf16x4*)(pw + c * 72 + mt * 16 + quad * 4) = pv;
    }
    const bf16_t* pr = pw + c * 72 + quad * 8;
    bf16x8 pa0 = *(const bf16x8*)pr;
    bf16x8 pa1 = *(const bf16x8*)(pr + 32);

    // O += P V (V B-frags are vectorized rows of Vs[d][j])
    #pragma unroll
    for (int nt = 0; nt < 4; ++nt) {
      const bf16_t* vr = vs + (nt * 16 + c) * 72 + quad * 8;
      bf16x8 vb0 = *(const bf16x8*)vr;
      bf16x8 vb1 = *(const bf16x8*)(vr + 32);
      o[nt] = __builtin_amdgcn_mfma_f32_16x16x32_bf16(pa0, vb0, o[nt], 0, 0, 0);
      o[nt] = __builtin_amdgcn_mfma_f32_16x16x32_bf16(pa1, vb1, o[nt], 0, 0, 0);
    }
    // no second barrier: next iter writes the other LDS buffer
  }

  // epilogue: AO[i][h*64+d] = O / l  (broadcast l to row layout)
  float lr[4];
  #pragma unroll
  for (int r = 0; r < 4; ++r) lr[r] = __shfl(lrow, quad * 4 + r);
  #pragma unroll
  for (int nt = 0; nt < 4; ++nt)
    #pragma unroll
    for (int r = 0; r < 4; ++r) {
      int i = i0 + wave * 16 + quad * 4 + r;
      AO[(size_t)(i * BATCH + b) * HID + h * HDIM + nt * 16 + c] =
          (bf16_t)(o[nt][r] / lr[r]);
    }
}

extern "C" void kernel_launch(void* const* d_in, const int* in_sizes, int n_in,
                              void* d_out, int out_size, void* d_ws, size_t ws_size,
                              hipStream_t stream) {
  const float* x      = (const float*)d_in[0];   // [2048][2][1024]
  const float* W_proj = (const float*)d_in[1];   // [1024][3072]
  const float* b_proj = (const float*)d_in[2];   // [3072]
  const float* W_out  = (const float*)d_in[3];   // [1024][1024]
  const float* b_out  = (const float*)d_in[4];   // [1024]

  bf16_t* Xb  = (bf16_t*)d_ws;                               // 4096*1024
  bf16_t* Wpt = Xb  + (size_t)NBROW * EMB;                   // 3072*1024
  bf16_t* Wot = Wpt + (size_t)3 * HID * EMB;                 // 1024*1024
  bf16_t* Pj  = Wot + (size_t)HID * EMB;                     // 4096*3072
  bf16_t* AO  = Pj  + (size_t)NBROW * 3 * HID;               // 4096*1024
  bf16_t* Vt  = AO  + (size_t)NBROW * HID;                   // 32*64*2048

  convert_bf16_kernel<<<(NBROW * EMB) / 1024, 256, 0, stream>>>(x, Xb);
  transpose_convert_kernel<<<dim3(3 * HID / 32, EMB / 32), 256, 0, stream>>>(
      W_proj, Wpt, EMB, 3 * HID);
  transpose_convert_kernel<<<dim3(EMB / 32, HID / 32), 256, 0, stream>>>(
      W_out, Wot, HID, EMB);
  gemm_bt_kernel<64, true><<<dim3(NBROW / 128, 3 * HID / 64), 256, 0, stream>>>(
      Xb, Wpt, b_proj, (void*)Pj, NBROW, 3 * HID, EMB);
  vt_transpose_kernel<<<dim3(N_SEQ / 32, HDIM / 32, BATCH * NHEAD), 256, 0, stream>>>(
      Pj, Vt);
  flash_attn_kernel<<<512, 512, 0, stream>>>(Pj, Vt, AO);
  gemm_bt_kernel<64, false><<<dim3(NBROW / 128, EMB / 64), 256, 0, stream>>>(
      AO, Wot, b_out, d_out, NBROW, EMB, HID);
}